// Round 1
// baseline (24125.597 us; speedup 1.0000x reference)
//
#include <hip/hip_runtime.h>
#include <hip/hip_bf16.h>

#define B 128
#define P 196
#define ENC 512
#define DEC 512
#define ATT 256
#define EMB 256
#define V 5000
#define S 256
#define S1 257
#define NG 2048      // 4*DEC
#define KTOT 1280    // EMB+ENC+DEC
#define KS 8
#define KCH 160      // KTOT/KS

// ---------------- mean over P ----------------
__global__ __launch_bounds__(256) void k_mean(const float* __restrict__ feat,
                                              float* __restrict__ mean_f) {
    int idx = blockIdx.x * 256 + threadIdx.x;     // over B*ENC
    int b = idx >> 9, e = idx & 511;
    const float* fp = feat + (size_t)b * P * ENC + e;
    float s = 0.f;
    for (int p = 0; p < P; ++p) s += fp[(size_t)p * ENC];
    mean_f[idx] = s * (1.0f / (float)P);
}

// ---------------- h0 / c0 ----------------
__global__ __launch_bounds__(256) void k_init_hc(const float* __restrict__ mean_f,
        const float* __restrict__ ih_w, const float* __restrict__ ih_b,
        const float* __restrict__ ic_w, const float* __restrict__ ic_b,
        float* __restrict__ h, float* __restrict__ c) {
    int idx = blockIdx.x * 256 + threadIdx.x;     // over B*DEC
    int b = idx >> 9, d = idx & 511;
    const float* mf = mean_f + (size_t)b * ENC;
    float sh = ih_b[d], sc = ic_b[d];
    for (int e = 0; e < ENC; ++e) {
        float m = mf[e];
        sh = fmaf(m, ih_w[(size_t)e * DEC + d], sh);
        sc = fmaf(m, ic_w[(size_t)e * DEC + d], sc);
    }
    h[idx] = sh; c[idx] = sc;
}

// ---------------- Uf = features @ Ua_w + Ua_b ----------------
__global__ __launch_bounds__(256) void k_uf(const float* __restrict__ feat,
        const float* __restrict__ Ua_w, const float* __restrict__ Ua_b,
        float* __restrict__ Uf) {
    int row0 = blockIdx.x * 8;                    // bp row base (B*P rows)
    int a = threadIdx.x;                          // 0..255 == ATT
    __shared__ float fs[8][ENC];
    for (int i = threadIdx.x; i < 8 * ENC; i += 256) {
        int r = i >> 9, e = i & 511;
        fs[r][e] = feat[(size_t)(row0 + r) * ENC + e];
    }
    __syncthreads();
    float acc[8];
    float bia = Ua_b[a];
#pragma unroll
    for (int r = 0; r < 8; ++r) acc[r] = bia;
    for (int e = 0; e < ENC; ++e) {
        float w = Ua_w[(size_t)e * ATT + a];
#pragma unroll
        for (int r = 0; r < 8; ++r) acc[r] = fmaf(fs[r][e], w, acc[r]);
    }
#pragma unroll
    for (int r = 0; r < 8; ++r) Uf[(size_t)(row0 + r) * ATT + a] = acc[r];
}

// ---------------- attention (per step): one block per batch row ----------------
__global__ __launch_bounds__(256) void k_attn(const float* __restrict__ h,
        const float* __restrict__ Uf, const float* __restrict__ feat,
        const float* __restrict__ Wa_w, const float* __restrict__ Wa_b,
        const float* __restrict__ va_w, const float* __restrict__ va_b,
        float* __restrict__ ctx) {
    int b = blockIdx.x;
    int tid = threadIdx.x;
    __shared__ float hs[DEC];
    __shared__ float wah[ATT];
    __shared__ float sc[P];
    __shared__ float red[8];
    for (int d = tid; d < DEC; d += 256) hs[d] = h[(size_t)b * DEC + d];
    __syncthreads();
    {   // wah[a] = Wa_b[a] + sum_d hs[d]*Wa_w[d,a]
        int a = tid;
        float s = Wa_b[a];
        for (int d = 0; d < DEC; ++d) s = fmaf(hs[d], Wa_w[(size_t)d * ATT + a], s);
        wah[a] = s;
    }
    __syncthreads();
    int wave = tid >> 6, lane = tid & 63;
    const float vb = va_b[0];
    // scores: wave w handles p = w, w+4, ...; lane covers 4 consecutive a
    for (int p = wave; p < P; p += 4) {
        const float* ufp = Uf + ((size_t)b * P + p) * ATT + lane * 4;
        float4 u = *(const float4*)ufp;
        float4 w4 = *(const float4*)&wah[lane * 4];
        float4 v4 = *(const float4*)&va_w[lane * 4];
        float s = v4.x * tanhf(u.x + w4.x) + v4.y * tanhf(u.y + w4.y)
                + v4.z * tanhf(u.z + w4.z) + v4.w * tanhf(u.w + w4.w);
#pragma unroll
        for (int off = 32; off; off >>= 1) s += __shfl_down(s, off);
        if (lane == 0) sc[p] = s + vb;
    }
    __syncthreads();
    // softmax over P
    float v = (tid < P) ? sc[tid] : -1e30f;
    float m = v;
#pragma unroll
    for (int off = 32; off; off >>= 1) m = fmaxf(m, __shfl_down(m, off));
    if (lane == 0) red[wave] = m;
    __syncthreads();
    if (tid == 0) {
        float mm = fmaxf(fmaxf(red[0], red[1]), fmaxf(red[2], red[3]));
        red[4] = mm;
    }
    __syncthreads();
    float mm = red[4];
    float e = (tid < P) ? __expf(v - mm) : 0.f;
    float ssum = e;
#pragma unroll
    for (int off = 32; off; off >>= 1) ssum += __shfl_down(ssum, off);
    if (lane == 0) red[wave] = ssum;
    __syncthreads();
    if (tid == 0) red[5] = 1.0f / (red[0] + red[1] + red[2] + red[3]);
    __syncthreads();
    float inv = red[5];
    if (tid < P) sc[tid] = e * inv;
    __syncthreads();
    // context
    float acc0 = 0.f, acc1 = 0.f;
    const float* fb = feat + (size_t)b * P * ENC;
    for (int p = 0; p < P; ++p) {
        float al = sc[p];
        acc0 = fmaf(al, fb[(size_t)p * ENC + tid], acc0);
        acc1 = fmaf(al, fb[(size_t)p * ENC + tid + 256], acc1);
    }
    ctx[(size_t)b * ENC + tid] = acc0;
    ctx[(size_t)b * ENC + tid + 256] = acc1;
}

// ---------------- gates partial GEMM: grid (32 n-tiles of 64, KS k-splits) ----------------
__global__ __launch_bounds__(256) void k_gates(const float* __restrict__ emb,
        const int* __restrict__ captions, int t,
        const float* __restrict__ ctx, const float* __restrict__ h,
        const float* __restrict__ W_ih, const float* __restrict__ W_hh,
        float* __restrict__ partials) {
    __shared__ float As[16][128];
    __shared__ float Bs[16][64];
    __shared__ int scap[B];
    int n0 = blockIdx.x * 64;
    int ks = blockIdx.y;
    int tid = threadIdx.x;
    if (tid < B) scap[tid] = captions[(size_t)tid * S1 + t];
    __syncthreads();
    int tx = tid & 15, ty = tid >> 4;
    float acc[8][4];
#pragma unroll
    for (int i = 0; i < 8; ++i)
#pragma unroll
        for (int j = 0; j < 4; ++j) acc[i][j] = 0.f;
    int arow = tid >> 1, ak = (tid & 1) * 8;
    int bkk = tid >> 4, bn = (tid & 15) * 4;
    for (int k0 = ks * KCH; k0 < ks * KCH + KCH; k0 += 16) {
        // A tile: A[b][k], gathered from emb / ctx / h (chunk never straddles source)
        const float* ap;
        if (k0 < EMB)            ap = emb + (size_t)scap[arow] * EMB + k0;
        else if (k0 < EMB + ENC) ap = ctx + (size_t)arow * ENC + (k0 - EMB);
        else                     ap = h + (size_t)arow * DEC + (k0 - EMB - ENC);
        float4 v0 = *(const float4*)(ap + ak);
        float4 v1 = *(const float4*)(ap + ak + 4);
        As[ak + 0][arow] = v0.x; As[ak + 1][arow] = v0.y;
        As[ak + 2][arow] = v0.z; As[ak + 3][arow] = v0.w;
        As[ak + 4][arow] = v1.x; As[ak + 5][arow] = v1.y;
        As[ak + 6][arow] = v1.z; As[ak + 7][arow] = v1.w;
        // B tile
        int k = k0 + bkk;
        const float* bp = (k < EMB + ENC) ? (W_ih + (size_t)k * NG + n0 + bn)
                                          : (W_hh + (size_t)(k - EMB - ENC) * NG + n0 + bn);
        *(float4*)&Bs[bkk][bn] = *(const float4*)bp;
        __syncthreads();
#pragma unroll
        for (int kk = 0; kk < 16; ++kk) {
            float4 a0 = *(const float4*)&As[kk][ty * 8];
            float4 a1 = *(const float4*)&As[kk][ty * 8 + 4];
            float4 b0 = *(const float4*)&Bs[kk][tx * 4];
            float av[8] = {a0.x, a0.y, a0.z, a0.w, a1.x, a1.y, a1.z, a1.w};
            float bv[4] = {b0.x, b0.y, b0.z, b0.w};
#pragma unroll
            for (int i = 0; i < 8; ++i)
#pragma unroll
                for (int j = 0; j < 4; ++j)
                    acc[i][j] = fmaf(av[i], bv[j], acc[i][j]);
        }
        __syncthreads();
    }
#pragma unroll
    for (int i = 0; i < 8; ++i) {
        int mrow = ty * 8 + i;
        float* pp = partials + ((size_t)ks * B + mrow) * NG + n0 + tx * 4;
        *(float4*)pp = make_float4(acc[i][0], acc[i][1], acc[i][2], acc[i][3]);
    }
}

// ---------------- reduce partials + LSTM cell ----------------
__global__ __launch_bounds__(256) void k_cell(const float* __restrict__ partials,
        const float* __restrict__ b_ih, const float* __restrict__ b_hh,
        float* __restrict__ h, float* __restrict__ c, float* __restrict__ Hout) {
    int idx = blockIdx.x * 256 + threadIdx.x;   // over B*DEC
    int b = idx >> 9, d = idx & 511;
    float si = b_ih[d] + b_hh[d];
    float sf = b_ih[d + DEC] + b_hh[d + DEC];
    float sg = b_ih[d + 2 * DEC] + b_hh[d + 2 * DEC];
    float so = b_ih[d + 3 * DEC] + b_hh[d + 3 * DEC];
#pragma unroll
    for (int ks = 0; ks < KS; ++ks) {
        const float* pp = partials + ((size_t)ks * B + b) * NG + d;
        si += pp[0]; sf += pp[DEC]; sg += pp[2 * DEC]; so += pp[3 * DEC];
    }
    float ii = 1.f / (1.f + __expf(-si));
    float ff = 1.f / (1.f + __expf(-sf));
    float gg = tanhf(sg);
    float oo = 1.f / (1.f + __expf(-so));
    float cn = ff * c[idx] + ii * gg;
    float hn = oo * tanhf(cn);
    c[idx] = cn; h[idx] = hn; Hout[idx] = hn;
}

// ---------------- output projection GEMM ----------------
// t_fix >= 0: A is h [B,DEC], rows are b, write out[:, t_fix, :]
// t_fix <  0: A is H [S*B, DEC] with row m=(t*B+b), write out[b, t, :]
__global__ __launch_bounds__(256) void k_fcn(const float* __restrict__ A,
        const float* __restrict__ Bw, const float* __restrict__ bias,
        float* __restrict__ out, int t_fix) {
    __shared__ float As[16][128];
    __shared__ float Bs[16][128];
    int m0 = blockIdx.x * 128;
    int n0 = blockIdx.y * 128;
    int tid = threadIdx.x;
    int tx = tid & 15, ty = tid >> 4;
    float acc[8][8];
#pragma unroll
    for (int i = 0; i < 8; ++i)
#pragma unroll
        for (int j = 0; j < 8; ++j) acc[i][j] = 0.f;
    int arow = tid >> 1, ak = (tid & 1) * 8;
    int bkk = tid >> 4, bn = (tid & 15) * 8;
    const float4 z4 = make_float4(0.f, 0.f, 0.f, 0.f);
    for (int k0 = 0; k0 < DEC; k0 += 16) {
        {
            const float* ap = A + (size_t)(m0 + arow) * DEC + k0 + ak;
            float4 v0 = *(const float4*)ap;
            float4 v1 = *(const float4*)(ap + 4);
            As[ak + 0][arow] = v0.x; As[ak + 1][arow] = v0.y;
            As[ak + 2][arow] = v0.z; As[ak + 3][arow] = v0.w;
            As[ak + 4][arow] = v1.x; As[ak + 5][arow] = v1.y;
            As[ak + 6][arow] = v1.z; As[ak + 7][arow] = v1.w;
        }
        {
            int n4 = n0 + bn;
            const float* bp = Bw + (size_t)(k0 + bkk) * V + n4;
            float4 v0 = (n4 < V) ? *(const float4*)bp : z4;
            float4 v1 = (n4 + 4 < V) ? *(const float4*)(bp + 4) : z4;
            *(float4*)&Bs[bkk][bn] = v0;
            *(float4*)&Bs[bkk][bn + 4] = v1;
        }
        __syncthreads();
#pragma unroll
        for (int kk = 0; kk < 16; ++kk) {
            float4 a0 = *(const float4*)&As[kk][ty * 8];
            float4 a1 = *(const float4*)&As[kk][ty * 8 + 4];
            float4 b0 = *(const float4*)&Bs[kk][tx * 8];
            float4 b1 = *(const float4*)&Bs[kk][tx * 8 + 4];
            float av[8] = {a0.x, a0.y, a0.z, a0.w, a1.x, a1.y, a1.z, a1.w};
            float bv[8] = {b0.x, b0.y, b0.z, b0.w, b1.x, b1.y, b1.z, b1.w};
#pragma unroll
            for (int i = 0; i < 8; ++i)
#pragma unroll
                for (int j = 0; j < 8; ++j)
                    acc[i][j] = fmaf(av[i], bv[j], acc[i][j]);
        }
        __syncthreads();
    }
#pragma unroll
    for (int i = 0; i < 8; ++i) {
        int mrow = m0 + ty * 8 + i;
        int bb, tt;
        if (t_fix >= 0) { bb = mrow; tt = t_fix; }
        else            { tt = mrow >> 7; bb = mrow & 127; }
        float* op = out + ((size_t)bb * S + tt) * V + n0 + tx * 8;
#pragma unroll
        for (int j = 0; j < 8; ++j) {
            int n = n0 + tx * 8 + j;
            if (n < V) op[j] = acc[i][j] + bias[n];
        }
    }
}

extern "C" void kernel_launch(void* const* d_in, const int* in_sizes, int n_in,
                              void* d_out, int out_size, void* d_ws, size_t ws_size,
                              hipStream_t stream) {
    const float* features = (const float*)d_in[0];
    const int*   captions = (const int*)d_in[1];
    const float* emb      = (const float*)d_in[2];
    const float* Ua_w     = (const float*)d_in[3];
    const float* Ua_b     = (const float*)d_in[4];
    const float* Wa_w     = (const float*)d_in[5];
    const float* Wa_b     = (const float*)d_in[6];
    const float* va_w     = (const float*)d_in[7];
    const float* va_b     = (const float*)d_in[8];
    const float* ih_w     = (const float*)d_in[9];
    const float* ih_b     = (const float*)d_in[10];
    const float* ic_w     = (const float*)d_in[11];
    const float* ic_b     = (const float*)d_in[12];
    const float* W_ih     = (const float*)d_in[13];
    const float* b_ih     = (const float*)d_in[14];
    const float* W_hh     = (const float*)d_in[15];
    const float* b_hh     = (const float*)d_in[16];
    const float* fcn_w    = (const float*)d_in[17];
    const float* fcn_b    = (const float*)d_in[18];
    float* out = (float*)d_out;
    float* ws  = (float*)d_ws;

    size_t off = 0;
    float* Uf       = ws + off; off += (size_t)B * P * ATT;     // 6,422,528
    float* partials = ws + off; off += (size_t)KS * B * NG;     // 2,097,152
    float* hbuf     = ws + off; off += (size_t)B * DEC;
    float* cbuf     = ws + off; off += (size_t)B * DEC;
    float* ctx      = ws + off; off += (size_t)B * ENC;
    float* meanf    = ws + off; off += (size_t)B * ENC;
    float* Hall     = ws + off; off += (size_t)S * B * DEC;     // 16,777,216
    bool bigws = ws_size >= off * sizeof(float);

    k_mean<<<256, 256, 0, stream>>>(features, meanf);
    k_init_hc<<<256, 256, 0, stream>>>(meanf, ih_w, ih_b, ic_w, ic_b, hbuf, cbuf);
    k_uf<<<3136, 256, 0, stream>>>(features, Ua_w, Ua_b, Uf);

    for (int t = 0; t < S; ++t) {
        k_attn<<<128, 256, 0, stream>>>(hbuf, Uf, features, Wa_w, Wa_b, va_w, va_b, ctx);
        k_gates<<<dim3(32, KS), 256, 0, stream>>>(emb, captions, t, ctx, hbuf, W_ih, W_hh, partials);
        float* Hout = bigws ? (Hall + (size_t)t * B * DEC) : hbuf;
        k_cell<<<256, 256, 0, stream>>>(partials, b_ih, b_hh, hbuf, cbuf, Hout);
        if (!bigws)
            k_fcn<<<dim3(1, 40), 256, 0, stream>>>(hbuf, fcn_w, fcn_b, out, t);
    }
    if (bigws)
        k_fcn<<<dim3(256, 40), 256, 0, stream>>>(Hall, fcn_w, fcn_b, out, -1);
}